// Round 16
// baseline (534.352 us; speedup 1.0000x reference)
//
#include <hip/hip_runtime.h>

#define N_NODES 100000
#define N_EDGES 640000
#define D 128
#define NLAYERS 4
#define NCH 8
#define CHSZ 12500               // source nodes per chunk (3.2 MB bf16 slice < 4 MB L2/XCD)
#define NBKT (NCH * N_NODES)     // 800000 buckets keyed (src_chunk, dst)

typedef __attribute__((ext_vector_type(8))) short short8;
typedef __attribute__((ext_vector_type(4))) float f32x4;

// f32 -> bf16 with round-to-nearest-even
__device__ __forceinline__ unsigned short cvbf(float f) {
    unsigned u = __float_as_uint(f);
    return (unsigned short)((u + 0x7fffu + ((u >> 16) & 1u)) >> 16);
}
__device__ __forceinline__ float bflo(unsigned u) {  // low bf16 of packed u32
    return __uint_as_float(u << 16);
}
__device__ __forceinline__ float bfhi(unsigned u) {  // high bf16 of packed u32
    return __uint_as_float(u & 0xffff0000u);
}

// ---------------- chunked CSR build: bucket b = (src/CHSZ)*N_NODES + dst ----------------
__global__ void count_kernel(const int* __restrict__ edge, int* __restrict__ cnt) {
    int e = blockIdx.x * 256 + threadIdx.x;
    if (e < N_EDGES) {
        int src = edge[e];
        int dst = edge[N_EDGES + e];
        atomicAdd(&cnt[(src / CHSZ) * N_NODES + dst], 1);
    }
}

// per-node total degree (sum over chunks) — consumed by the layer kernel
__global__ void deg_kernel(const int* __restrict__ cnt, int* __restrict__ deg) {
    int v = blockIdx.x * 256 + threadIdx.x;
    if (v < N_NODES) {
        int d = 0;
#pragma unroll
        for (int c = 0; c < NCH; ++c) d += cnt[c * N_NODES + v];
        deg[v] = d;
    }
}

__global__ void scan_local(const int* __restrict__ cnt, int* __restrict__ rp,
                           int* __restrict__ bsum, int n) {
    __shared__ int tsum[256];
    int t = threadIdx.x;
    int base = blockIdx.x * 1024 + t * 4;
    int v[4];
#pragma unroll
    for (int j = 0; j < 4; ++j) {
        int i = base + j;
        v[j] = (i < n) ? cnt[i] : 0;
    }
    int ts = v[0] + v[1] + v[2] + v[3];
    tsum[t] = ts;
    __syncthreads();
    for (int off = 1; off < 256; off <<= 1) {
        int add = (t >= off) ? tsum[t - off] : 0;
        __syncthreads();
        tsum[t] += add;
        __syncthreads();
    }
    int incl = tsum[t];
    int run = incl - ts;
#pragma unroll
    for (int j = 0; j < 4; ++j) {
        int i = base + j;
        if (i < n) rp[i] = run;
        run += v[j];
    }
    if (t == 255) bsum[blockIdx.x] = incl;
}

// single-block parallel exclusive scan of per-block sums (nb <= 1024)
__global__ void scan_bsums(int* __restrict__ bsum, int nb) {
    __shared__ int tsum[256];
    int t = threadIdx.x;
    int base = t * 4;
    int v[4];
#pragma unroll
    for (int j = 0; j < 4; ++j) v[j] = (base + j < nb) ? bsum[base + j] : 0;
    int ts = v[0] + v[1] + v[2] + v[3];
    tsum[t] = ts;
    __syncthreads();
    for (int off = 1; off < 256; off <<= 1) {
        int add = (t >= off) ? tsum[t - off] : 0;
        __syncthreads();
        tsum[t] += add;
        __syncthreads();
    }
    int run = tsum[t] - ts;  // exclusive
#pragma unroll
    for (int j = 0; j < 4; ++j) {
        if (base + j < nb) {
            int x = v[j];
            bsum[base + j] = run;
            run += x;
        }
    }
}

__global__ void scan_add(int* __restrict__ rp, int* __restrict__ fill,
                         const int* __restrict__ bsum, int n, int total) {
    int add = bsum[blockIdx.x];
    int base = blockIdx.x * 1024;
#pragma unroll
    for (int j = 0; j < 4; ++j) {
        int i = base + j * 256 + threadIdx.x;
        if (i < n) {
            int v = rp[i] + add;
            rp[i] = v;
            fill[i] = v;
        }
    }
    if (blockIdx.x == 0 && threadIdx.x == 0) rp[n] = total;
}

__global__ void fill_kernel(const int* __restrict__ edge, int* __restrict__ fill,
                            int* __restrict__ col) {
    int e = blockIdx.x * 256 + threadIdx.x;
    if (e < N_EDGES) {
        int src = edge[e];
        int dst = edge[N_EDGES + e];
        int b = (src / CHSZ) * N_NODES + dst;
        int slot = atomicAdd(&fill[b], 1);
        col[slot] = src;
    }
}

// ---------------- all weights fp32 -> bf16, one dispatch ----------------
__global__ void wconv_all(const float* __restrict__ Wi, const float* __restrict__ Wm,
                          const float* __restrict__ Wu, unsigned short* __restrict__ Wi_bf,
                          unsigned short* __restrict__ Wm_bf,
                          unsigned short* __restrict__ Wu_bf) {
    const int nWi = D * D / 4;            // 4096
    const int nWm = NLAYERS * D * D / 4;  // 16384
    int i = blockIdx.x * 256 + threadIdx.x;
    const float* src;
    unsigned short* dst;
    int o;
    if (i < nWi) {
        src = Wi; dst = Wi_bf; o = i;
    } else if (i < nWi + nWm) {
        src = Wm; dst = Wm_bf; o = i - nWi;
    } else if (i < nWi + 2 * nWm) {
        src = Wu; dst = Wu_bf; o = i - nWi - nWm;
    } else {
        return;
    }
    float4 v = ((const float4*)src)[o];
    ushort4 ob;
    ob.x = cvbf(v.x);
    ob.y = cvbf(v.y);
    ob.z = cvbf(v.z);
    ob.w = cvbf(v.w);
    ((ushort4*)dst)[o] = ob;
}

// ---------------- input projection: outb = bf16(x @ W1^T + b1) ----------------
__global__ __launch_bounds__(256, 4) void proj_k(const float* __restrict__ Asrc,
                                                 const short* __restrict__ W1b,
                                                 const float* __restrict__ b1,
                                                 unsigned* __restrict__ outb, int nrows) {
    __shared__ __align__(16) char smem[32768];
    short8* As = (short8*)smem;  // 16 KB
    float* Of = (float*)smem;    // 32 KB after barrier
    int t = threadIdx.x;
    int rowbase = blockIdx.x * 64;

#pragma unroll
    for (int ch = 0; ch < 4; ++ch) {
        int flat = ch * 256 + t;
        int r = flat >> 4, g = flat & 15;
        int gr = rowbase + r;
        short8 frag = {0, 0, 0, 0, 0, 0, 0, 0};
        if (gr < nrows) {
            const float4* src = (const float4*)Asrc;
            float4 a0 = src[(size_t)gr * 32 + g * 2];
            float4 a1 = src[(size_t)gr * 32 + g * 2 + 1];
            frag[0] = (short)cvbf(a0.x);
            frag[1] = (short)cvbf(a0.y);
            frag[2] = (short)cvbf(a0.z);
            frag[3] = (short)cvbf(a0.w);
            frag[4] = (short)cvbf(a1.x);
            frag[5] = (short)cvbf(a1.y);
            frag[6] = (short)cvbf(a1.z);
            frag[7] = (short)cvbf(a1.w);
        }
        As[r * 16 + (g ^ (r & 7))] = frag;
    }

    int lane = t & 63;
    int w = t >> 6;
    int c0 = w * 32;
    int lrow = lane & 15;
    int lk = lane >> 4;
    int swz = lrow & 7;

    const short8* W1v = (const short8*)W1b;
    short8 bw[2][4];
#pragma unroll
    for (int ct = 0; ct < 2; ++ct)
#pragma unroll
        for (int ks = 0; ks < 4; ++ks)
            bw[ct][ks] = W1v[(size_t)(c0 + ct * 16 + lrow) * 16 + ks * 4 + lk];

    __syncthreads();

    f32x4 zero4 = {0.f, 0.f, 0.f, 0.f};
    f32x4 acc[4][2];
#pragma unroll
    for (int rt = 0; rt < 4; ++rt) {
        acc[rt][0] = zero4;
        acc[rt][1] = zero4;
    }
#pragma unroll
    for (int ks = 0; ks < 4; ++ks) {
        short8 a[4];
#pragma unroll
        for (int rt = 0; rt < 4; ++rt)
            a[rt] = As[(rt * 16 + lrow) * 16 + ((ks * 4 + lk) ^ swz)];
#pragma unroll
        for (int rt = 0; rt < 4; ++rt) {
            acc[rt][0] = __builtin_amdgcn_mfma_f32_16x16x32_bf16(a[rt], bw[0][ks], acc[rt][0], 0, 0, 0);
            acc[rt][1] = __builtin_amdgcn_mfma_f32_16x16x32_bf16(a[rt], bw[1][ks], acc[rt][1], 0, 0, 0);
        }
    }

    float b1v[2] = {b1[c0 + lrow], b1[c0 + 16 + lrow]};
    __syncthreads();
#pragma unroll
    for (int rt = 0; rt < 4; ++rt) {
#pragma unroll
        for (int ct = 0; ct < 2; ++ct) {
            int c = c0 + ct * 16 + lrow;
#pragma unroll
            for (int reg = 0; reg < 4; ++reg) {
                int row = rt * 16 + lk * 4 + reg;
                Of[row * 128 + ((c + ((row >> 2) & 3) * 8) & 127)] = acc[rt][ct][reg] + b1v[ct];
            }
        }
    }
    __syncthreads();

    // readout: 8 fp32 per lane -> packed bf16 uint4 store (16B/lane)
#pragma unroll
    for (int ch = 0; ch < 4; ++ch) {
        int flat = ch * 256 + t;  // 0..1023 : 64 rows x 16 col-granules(8)
        int row = flat >> 4;
        int cg = flat & 15;
        int grow = rowbase + row;
        if (grow >= nrows) continue;
        int fo = row * 128 + ((cg * 8 + ((row >> 2) & 3) * 8) & 127);
        float4 v0 = *(const float4*)&Of[fo];
        float4 v1 = *(const float4*)&Of[fo + 4];
        uint4 ob;
        ob.x = ((unsigned)cvbf(v0.y) << 16) | (unsigned)cvbf(v0.x);
        ob.y = ((unsigned)cvbf(v0.w) << 16) | (unsigned)cvbf(v0.z);
        ob.z = ((unsigned)cvbf(v1.y) << 16) | (unsigned)cvbf(v1.x);
        ob.w = ((unsigned)cvbf(v1.w) << 16) | (unsigned)cvbf(v1.z);
        ((uint4*)outb)[(size_t)grow * 16 + cg] = ob;
    }
}

// ---------------- fused GNN layer: source-chunked gather (L2-resident slices) --------
// Gather: for each of 8 source-chunks, the wave walks its 16 dst nodes' contiguous
// edge range ((chunk,dst)-sorted CSR), accumulating the current node in registers and
// flushing at node boundaries into a 32 KB wave-private fp32 LDS accumulator. Per-chunk
// barriers keep a block's waves on the same 3.2 MB source slice -> L2-hit gathers.
// Then convert (inv_deg, bf16) -> As -> GEMM1 -> Ts -> GEMM2 -> Os -> epilogue.
// Mid layers: bf16 carry to hb_out (ping-pong, != hb_in). Last: fp32 to outf.
__global__ __launch_bounds__(256, 3) void gnnlayer_k(
    const unsigned* __restrict__ hb_in, const int* __restrict__ rp, const int* __restrict__ col,
    const int* __restrict__ deg_g, const short* __restrict__ W1b, const float* __restrict__ b1,
    const short* __restrict__ W2b, const float* __restrict__ b2,
    float* __restrict__ outf, unsigned* __restrict__ hb_out, int nrows) {
    __shared__ __align__(16) char smem[16384];       // As -> Ts -> Os (phase-aliased)
    __shared__ __align__(16) float2 accF[64 * 64];   // 32 KB fp32 accum, wave-private rows
    __shared__ float dflag[64];
    __shared__ int rbl[4 * 17];
    short8* As = (short8*)smem;
    short* TsS = (short*)smem;
    unsigned short* Os = (unsigned short*)smem;
    int t = threadIdx.x;
    int rowbase = blockIdx.x * 64;
    int lane = t & 63;
    int wv = __builtin_amdgcn_readfirstlane(t >> 6);  // 0..3
    int nbase = rowbase + wv * 16;

    // zero this wave's accumulator rows (wave-private; ordered by same-lane LDS deps)
#pragma unroll
    for (int i = 0; i < 16; ++i) accF[(wv * 16 + i) * 64 + lane] = make_float2(0.f, 0.f);

    // ---- chunked gather-aggregate ----
    for (int c = 0; c < NCH; ++c) {
        if (lane < 17) rbl[wv * 17 + lane] = rp[c * N_NODES + min(nbase + lane, N_NODES)];
        __syncthreads();
        int startj = __builtin_amdgcn_readfirstlane(rbl[wv * 17]);
        int endj = __builtin_amdgcn_readfirstlane(rbl[wv * 17 + 16]);
        int T = endj - startj;
        if (T > 0) {
            constexpr int U = 16;
            int cur = 0;
            int cur_end = __builtin_amdgcn_readfirstlane(rbl[wv * 17 + 1]);
            float ax = 0.f, ay = 0.f;
            int u[U];
#pragma unroll
            for (int k = 0; k < U; ++k) u[k] = (k < T) ? col[startj + k] : 0;
            for (int jg = 0; jg < T; jg += U) {
                unsigned p[U];
                // issue the group's gathers first (independent -> in flight together)
#pragma unroll
                for (int k = 0; k < U; ++k)
                    p[k] = (jg + k < T) ? hb_in[(size_t)u[k] * 64 + lane] : 0u;
                // prefetch next group's col indices
#pragma unroll
                for (int k = 0; k < U; ++k) {
                    int jn = jg + U + k;
                    if (jn < T) u[k] = col[startj + jn];
                }
                // accumulate; flush at node boundaries (uniform control)
#pragma unroll
                for (int k = 0; k < U; ++k) {
                    if (jg + k >= T) break;
                    int ja = startj + jg + k;
                    while (ja >= cur_end) {
                        float2 aold = accF[(wv * 16 + cur) * 64 + lane];
                        aold.x += ax;
                        aold.y += ay;
                        accF[(wv * 16 + cur) * 64 + lane] = aold;
                        ax = 0.f;
                        ay = 0.f;
                        ++cur;
                        cur_end = __builtin_amdgcn_readfirstlane(rbl[wv * 17 + cur + 1]);
                    }
                    ax += bflo(p[k]);
                    ay += bfhi(p[k]);
                }
            }
            // trailing flush for the current node
            float2 aold = accF[(wv * 16 + cur) * 64 + lane];
            aold.x += ax;
            aold.y += ay;
            accF[(wv * 16 + cur) * 64 + lane] = aold;
        }
        __syncthreads();  // keep the block's waves chunk-aligned (L2 slice residency)
    }

    // per-node total degree (uniform scalar loads, statically indexed)
    int dvs[16];
#pragma unroll
    for (int i = 0; i < 16; ++i)
        dvs[i] = __builtin_amdgcn_readfirstlane(deg_g[min(nbase + i, N_NODES - 1)]);

    // convert: mean (inv_deg) -> packed bf16 -> swizzled As tile; dflag from degree
    {
        unsigned* AsU = (unsigned*)As;
        int g = lane >> 2;
        int dw = lane & 3;
#pragma unroll
        for (int i = 0; i < 16; ++i) {
            int r = wv * 16 + i;
            float2 a = accF[r * 64 + lane];
            float inv = 1.0f / fmaxf((float)dvs[i], 1.0f);
            unsigned pv = ((unsigned)cvbf(a.y * inv) << 16) | (unsigned)cvbf(a.x * inv);
            AsU[(r * 16 + (g ^ (r & 7))) * 4 + dw] = pv;
            if (lane == 0) dflag[r] = (dvs[i] > 0) ? 1.0f : 0.0f;
        }
    }

    int c0 = wv * 32;
    int lrow = lane & 15;
    int lk = lane >> 4;
    int swz = lrow & 7;

    const short8* W1v = (const short8*)W1b;
    short8 bw[2][4];
#pragma unroll
    for (int ct = 0; ct < 2; ++ct)
#pragma unroll
        for (int ks = 0; ks < 4; ++ks)
            bw[ct][ks] = W1v[(size_t)(c0 + ct * 16 + lrow) * 16 + ks * 4 + lk];

    __syncthreads();  // As + dflag complete

    f32x4 zero4 = {0.f, 0.f, 0.f, 0.f};
    f32x4 acc[4][2];
#pragma unroll
    for (int rt = 0; rt < 4; ++rt) {
        acc[rt][0] = zero4;
        acc[rt][1] = zero4;
    }
#pragma unroll
    for (int ks = 0; ks < 4; ++ks) {
        short8 a[4];
#pragma unroll
        for (int rt = 0; rt < 4; ++rt)
            a[rt] = As[(rt * 16 + lrow) * 16 + ((ks * 4 + lk) ^ swz)];
#pragma unroll
        for (int rt = 0; rt < 4; ++rt) {
            acc[rt][0] = __builtin_amdgcn_mfma_f32_16x16x32_bf16(a[rt], bw[0][ks], acc[rt][0], 0, 0, 0);
            acc[rt][1] = __builtin_amdgcn_mfma_f32_16x16x32_bf16(a[rt], bw[1][ks], acc[rt][1], 0, 0, 0);
        }
    }

    const short8* W2v = (const short8*)W2b;
    short8 bw2[2][4];
#pragma unroll
    for (int ct = 0; ct < 2; ++ct)
#pragma unroll
        for (int ks = 0; ks < 4; ++ks)
            bw2[ct][ks] = W2v[(size_t)(c0 + ct * 16 + lrow) * 16 + ks * 4 + lk];

    float b1v[2] = {b1[c0 + lrow], b1[c0 + 16 + lrow]};
    __syncthreads();  // all As reads done; region becomes T tile
#pragma unroll
    for (int rt = 0; rt < 4; ++rt) {
#pragma unroll
        for (int ct = 0; ct < 2; ++ct) {
            int c = c0 + ct * 16 + lrow;
            int gh = c >> 3;
#pragma unroll
            for (int reg = 0; reg < 4; ++reg) {
                int rl = rt * 16 + lk * 4 + reg;  // C/D: row=(lane>>4)*4+reg
                float tv = acc[rt][ct][reg] + b1v[ct] * dflag[rl];
                TsS[rl * 128 + ((gh ^ (rl & 7)) << 3) + (c & 7)] = (short)cvbf(tv);
            }
        }
    }
    __syncthreads();  // T complete

    f32x4 acc2[4][2];
#pragma unroll
    for (int rt = 0; rt < 4; ++rt) {
        acc2[rt][0] = zero4;
        acc2[rt][1] = zero4;
    }
#pragma unroll
    for (int ks = 0; ks < 4; ++ks) {
        short8 a[4];
#pragma unroll
        for (int rt = 0; rt < 4; ++rt)
            a[rt] = As[(rt * 16 + lrow) * 16 + ((ks * 4 + lk) ^ swz)];  // region holds T now
#pragma unroll
        for (int rt = 0; rt < 4; ++rt) {
            acc2[rt][0] = __builtin_amdgcn_mfma_f32_16x16x32_bf16(a[rt], bw2[0][ks], acc2[rt][0], 0, 0, 0);
            acc2[rt][1] = __builtin_amdgcn_mfma_f32_16x16x32_bf16(a[rt], bw2[1][ks], acc2[rt][1], 0, 0, 0);
        }
    }

    float b2v[2] = {b2[c0 + lrow], b2[c0 + 16 + lrow]};
    __syncthreads();  // all T reads done; region becomes s tile (bf16)
#pragma unroll
    for (int rt = 0; rt < 4; ++rt) {
#pragma unroll
        for (int ct = 0; ct < 2; ++ct) {
            int c = c0 + ct * 16 + lrow;
            int gh = c >> 3;
#pragma unroll
            for (int reg = 0; reg < 4; ++reg) {
                int rl = rt * 16 + lk * 4 + reg;
                Os[rl * 128 + ((gh ^ (rl & 7)) << 3) + (c & 7)] =
                    cvbf(acc2[rt][ct][reg] + b2v[ct]);
            }
        }
    }
    __syncthreads();

    // epilogue: o = h_own + relu(s). 16B/lane accesses throughout.
    const uint4* Hb16 = (const uint4*)hb_in;
#pragma unroll
    for (int ch = 0; ch < 4; ++ch) {
        int flat = ch * 256 + t;  // 0..1023 : 64 rows x 16 col-granules(8)
        int row = flat >> 4;
        int cg = flat & 15;
        int grow = rowbase + row;
        if (grow >= nrows) continue;
        uint4 sv = *(const uint4*)&Os[row * 128 + ((cg ^ (row & 7)) << 3)];
        uint4 hv = Hb16[(size_t)grow * 16 + cg];
        float o[8];
        const unsigned* sp = (const unsigned*)&sv;
        const unsigned* hp = (const unsigned*)&hv;
#pragma unroll
        for (int j = 0; j < 4; ++j) {
            o[2 * j + 0] = bflo(hp[j]) + fmaxf(bflo(sp[j]), 0.f);
            o[2 * j + 1] = bfhi(hp[j]) + fmaxf(bfhi(sp[j]), 0.f);
        }
        if (hb_out) {
            uint4 ob;
            ob.x = ((unsigned)cvbf(o[1]) << 16) | (unsigned)cvbf(o[0]);
            ob.y = ((unsigned)cvbf(o[3]) << 16) | (unsigned)cvbf(o[2]);
            ob.z = ((unsigned)cvbf(o[5]) << 16) | (unsigned)cvbf(o[4]);
            ob.w = ((unsigned)cvbf(o[7]) << 16) | (unsigned)cvbf(o[6]);
            ((uint4*)hb_out)[(size_t)grow * 16 + cg] = ob;
        }
        if (outf) {
            float4 f0 = make_float4(o[0], o[1], o[2], o[3]);
            float4 f1 = make_float4(o[4], o[5], o[6], o[7]);
            ((float4*)outf)[(size_t)grow * 32 + cg * 2 + 0] = f0;
            ((float4*)outf)[(size_t)grow * 32 + cg * 2 + 1] = f1;
        }
    }
}

extern "C" void kernel_launch(void* const* d_in, const int* in_sizes, int n_in,
                              void* d_out, int out_size, void* d_ws, size_t ws_size,
                              hipStream_t stream) {
    const float* x = (const float*)d_in[0];
    const float* Wi = (const float*)d_in[1];
    const float* bi = (const float*)d_in[2];
    const float* Wm = (const float*)d_in[3];
    const float* bm = (const float*)d_in[4];
    const float* Wu = (const float*)d_in[5];
    const float* bu = (const float*)d_in[6];
    const int* edge = (const int*)d_in[7];
    float* h = (float*)d_out;

    char* ws = (char*)d_ws;
    size_t off = 0;
    auto alloc = [&](size_t bytes) {
        void* p = ws + off;
        off += (bytes + 255) & ~(size_t)255;
        return p;
    };
    // ping-pong bf16 h buffers (the carried representation between layers)
    unsigned* hbuf[2];
    hbuf[0] = (unsigned*)alloc((size_t)N_NODES * D * 2);
    hbuf[1] = (unsigned*)alloc((size_t)N_NODES * D * 2);
    unsigned short* Wi_bf = (unsigned short*)alloc((size_t)D * D * 2);
    unsigned short* Wm_bf = (unsigned short*)alloc((size_t)NLAYERS * D * D * 2);
    unsigned short* Wu_bf = (unsigned short*)alloc((size_t)NLAYERS * D * D * 2);
    int* cnt = (int*)alloc((size_t)NBKT * sizeof(int));
    int* rp = (int*)alloc((size_t)(NBKT + 1) * sizeof(int));
    int* fill = (int*)alloc((size_t)NBKT * sizeof(int));
    int* bsum = (int*)alloc(1024 * sizeof(int));
    int* col = (int*)alloc((size_t)N_EDGES * sizeof(int));
    int* deg = (int*)alloc((size_t)N_NODES * sizeof(int));

    const int scan_blocks = (NBKT + 1023) / 1024;    // 782
    const int edge_blocks = (N_EDGES + 255) / 256;   // 2500
    const int node_blocks = (N_NODES + 255) / 256;   // 391
    const int gemm_blocks = (N_NODES + 63) / 64;     // 1563
    const int wconv_n = (D * D / 4) * 9;             // 36864 float4s
    const int wconv_blocks = (wconv_n + 255) / 256;  // 144

    // chunked CSR build
    hipMemsetAsync(cnt, 0, (size_t)NBKT * sizeof(int), stream);
    count_kernel<<<edge_blocks, 256, 0, stream>>>(edge, cnt);
    deg_kernel<<<node_blocks, 256, 0, stream>>>(cnt, deg);
    scan_local<<<scan_blocks, 256, 0, stream>>>(cnt, rp, bsum, NBKT);
    scan_bsums<<<1, 256, 0, stream>>>(bsum, scan_blocks);
    scan_add<<<scan_blocks, 256, 0, stream>>>(rp, fill, bsum, NBKT, N_EDGES);
    fill_kernel<<<edge_blocks, 256, 0, stream>>>(edge, fill, col);

    // all weights -> bf16 in one dispatch
    wconv_all<<<wconv_blocks, 256, 0, stream>>>(Wi, Wm, Wu, Wi_bf, Wm_bf, Wu_bf);

    // input projection: hbuf[0] = bf16(x @ Wi^T + bi)
    proj_k<<<gemm_blocks, 256, 0, stream>>>(x, (const short*)Wi_bf, bi, hbuf[0], N_NODES);

    for (int l = 0; l < NLAYERS; ++l) {
        // layer l: read hbuf[l&1]; mid -> bf16 carry into hbuf[(l+1)&1]; last -> fp32 d_out
        unsigned* hb_out = (l == NLAYERS - 1) ? nullptr : hbuf[(l + 1) & 1];
        float* outf = (l == NLAYERS - 1) ? h : nullptr;
        gnnlayer_k<<<gemm_blocks, 256, 0, stream>>>(
            hbuf[l & 1], rp, col, deg,
            (const short*)(Wm_bf + (size_t)l * D * D), bm + (size_t)l * D,
            (const short*)(Wu_bf + (size_t)l * D * D), bu + (size_t)l * D, outf, hb_out,
            N_NODES);
    }
}

// Round 17
// 297.874 us; speedup vs baseline: 1.7939x; 1.7939x over previous
//
#include <hip/hip_runtime.h>

#define N_NODES 100000
#define N_EDGES 640000
#define D 128
#define NLAYERS 4

typedef __attribute__((ext_vector_type(8))) short short8;
typedef __attribute__((ext_vector_type(4))) float f32x4;

// f32 -> bf16 with round-to-nearest-even
__device__ __forceinline__ unsigned short cvbf(float f) {
    unsigned u = __float_as_uint(f);
    return (unsigned short)((u + 0x7fffu + ((u >> 16) & 1u)) >> 16);
}
__device__ __forceinline__ float bflo(unsigned u) {  // low bf16 of packed u32
    return __uint_as_float(u << 16);
}
__device__ __forceinline__ float bfhi(unsigned u) {  // high bf16 of packed u32
    return __uint_as_float(u & 0xffff0000u);
}

// ---------------- CSR build ----------------
__global__ void count_kernel(const int* __restrict__ edge, int* __restrict__ cnt) {
    int e = blockIdx.x * 256 + threadIdx.x;
    if (e < N_EDGES) atomicAdd(&cnt[edge[N_EDGES + e]], 1);
}

__global__ void scan_local(const int* __restrict__ cnt, int* __restrict__ rp,
                           int* __restrict__ bsum) {
    __shared__ int tsum[256];
    int t = threadIdx.x;
    int base = blockIdx.x * 1024 + t * 4;
    int v[4];
#pragma unroll
    for (int j = 0; j < 4; ++j) {
        int i = base + j;
        v[j] = (i < N_NODES) ? cnt[i] : 0;
    }
    int ts = v[0] + v[1] + v[2] + v[3];
    tsum[t] = ts;
    __syncthreads();
    for (int off = 1; off < 256; off <<= 1) {
        int add = (t >= off) ? tsum[t - off] : 0;
        __syncthreads();
        tsum[t] += add;
        __syncthreads();
    }
    int incl = tsum[t];
    int run = incl - ts;
#pragma unroll
    for (int j = 0; j < 4; ++j) {
        int i = base + j;
        if (i < N_NODES) rp[i] = run;
        run += v[j];
    }
    if (t == 255) bsum[blockIdx.x] = incl;
}

// adds prefix of bsum (per-block inclusive sums) computed in-kernel
__global__ void scan_add(int* __restrict__ rp, int* __restrict__ fill,
                         const int* __restrict__ bsum) {
    int add = 0;
    for (int b = 0; b < blockIdx.x; ++b) add += bsum[b];  // uniform scalar loop (98 max)
    int base = blockIdx.x * 1024;
#pragma unroll
    for (int j = 0; j < 4; ++j) {
        int i = base + j * 256 + threadIdx.x;
        if (i < N_NODES) {
            int v = rp[i] + add;
            rp[i] = v;
            fill[i] = v;
        }
    }
    if (blockIdx.x == 0 && threadIdx.x == 0) rp[N_NODES] = N_EDGES;
}

__global__ void fill_kernel(const int* __restrict__ edge, int* __restrict__ fill,
                            int* __restrict__ col) {
    int e = blockIdx.x * 256 + threadIdx.x;
    if (e < N_EDGES) {
        int dst = edge[N_EDGES + e];
        int slot = atomicAdd(&fill[dst], 1);
        col[slot] = edge[e];
    }
}

// ---------------- all weights fp32 -> bf16, one dispatch ----------------
__global__ void wconv_all(const float* __restrict__ Wi, const float* __restrict__ Wm,
                          const float* __restrict__ Wu, unsigned short* __restrict__ Wi_bf,
                          unsigned short* __restrict__ Wm_bf,
                          unsigned short* __restrict__ Wu_bf) {
    const int nWi = D * D / 4;            // 4096
    const int nWm = NLAYERS * D * D / 4;  // 16384
    int i = blockIdx.x * 256 + threadIdx.x;
    const float* src;
    unsigned short* dst;
    int o;
    if (i < nWi) {
        src = Wi; dst = Wi_bf; o = i;
    } else if (i < nWi + nWm) {
        src = Wm; dst = Wm_bf; o = i - nWi;
    } else if (i < nWi + 2 * nWm) {
        src = Wu; dst = Wu_bf; o = i - nWi - nWm;
    } else {
        return;
    }
    float4 v = ((const float4*)src)[o];
    ushort4 ob;
    ob.x = cvbf(v.x);
    ob.y = cvbf(v.y);
    ob.z = cvbf(v.z);
    ob.w = cvbf(v.w);
    ((ushort4*)dst)[o] = ob;
}

// ---------------- input projection: outb = bf16(x @ W1^T + b1) ----------------
__global__ __launch_bounds__(256, 4) void proj_k(const float* __restrict__ Asrc,
                                                 const short* __restrict__ W1b,
                                                 const float* __restrict__ b1,
                                                 unsigned* __restrict__ outb, int nrows) {
    __shared__ __align__(16) char smem[32768];
    short8* As = (short8*)smem;  // 16 KB
    float* Of = (float*)smem;    // 32 KB after barrier
    int t = threadIdx.x;
    int rowbase = blockIdx.x * 64;

#pragma unroll
    for (int ch = 0; ch < 4; ++ch) {
        int flat = ch * 256 + t;
        int r = flat >> 4, g = flat & 15;
        int gr = rowbase + r;
        short8 frag = {0, 0, 0, 0, 0, 0, 0, 0};
        if (gr < nrows) {
            const float4* src = (const float4*)Asrc;
            float4 a0 = src[(size_t)gr * 32 + g * 2];
            float4 a1 = src[(size_t)gr * 32 + g * 2 + 1];
            frag[0] = (short)cvbf(a0.x);
            frag[1] = (short)cvbf(a0.y);
            frag[2] = (short)cvbf(a0.z);
            frag[3] = (short)cvbf(a0.w);
            frag[4] = (short)cvbf(a1.x);
            frag[5] = (short)cvbf(a1.y);
            frag[6] = (short)cvbf(a1.z);
            frag[7] = (short)cvbf(a1.w);
        }
        As[r * 16 + (g ^ (r & 7))] = frag;
    }

    int lane = t & 63;
    int w = t >> 6;
    int c0 = w * 32;
    int lrow = lane & 15;
    int lk = lane >> 4;
    int swz = lrow & 7;

    const short8* W1v = (const short8*)W1b;
    short8 bw[2][4];
#pragma unroll
    for (int ct = 0; ct < 2; ++ct)
#pragma unroll
        for (int ks = 0; ks < 4; ++ks)
            bw[ct][ks] = W1v[(size_t)(c0 + ct * 16 + lrow) * 16 + ks * 4 + lk];

    __syncthreads();

    f32x4 zero4 = {0.f, 0.f, 0.f, 0.f};
    f32x4 acc[4][2];
#pragma unroll
    for (int rt = 0; rt < 4; ++rt) {
        acc[rt][0] = zero4;
        acc[rt][1] = zero4;
    }
#pragma unroll
    for (int ks = 0; ks < 4; ++ks) {
        short8 a[4];
#pragma unroll
        for (int rt = 0; rt < 4; ++rt)
            a[rt] = As[(rt * 16 + lrow) * 16 + ((ks * 4 + lk) ^ swz)];
#pragma unroll
        for (int rt = 0; rt < 4; ++rt) {
            acc[rt][0] = __builtin_amdgcn_mfma_f32_16x16x32_bf16(a[rt], bw[0][ks], acc[rt][0], 0, 0, 0);
            acc[rt][1] = __builtin_amdgcn_mfma_f32_16x16x32_bf16(a[rt], bw[1][ks], acc[rt][1], 0, 0, 0);
        }
    }

    float b1v[2] = {b1[c0 + lrow], b1[c0 + 16 + lrow]};
    __syncthreads();
#pragma unroll
    for (int rt = 0; rt < 4; ++rt) {
#pragma unroll
        for (int ct = 0; ct < 2; ++ct) {
            int c = c0 + ct * 16 + lrow;
#pragma unroll
            for (int reg = 0; reg < 4; ++reg) {
                int row = rt * 16 + lk * 4 + reg;
                Of[row * 128 + ((c + ((row >> 2) & 3) * 8) & 127)] = acc[rt][ct][reg] + b1v[ct];
            }
        }
    }
    __syncthreads();

    // readout: 8 fp32 per lane -> packed bf16 uint4 store (16B/lane)
#pragma unroll
    for (int ch = 0; ch < 4; ++ch) {
        int flat = ch * 256 + t;  // 0..1023 : 64 rows x 16 col-granules(8)
        int row = flat >> 4;
        int cg = flat & 15;
        int grow = rowbase + row;
        if (grow >= nrows) continue;
        int fo = row * 128 + ((cg * 8 + ((row >> 2) & 3) * 8) & 127);
        float4 v0 = *(const float4*)&Of[fo];
        float4 v1 = *(const float4*)&Of[fo + 4];
        uint4 ob;
        ob.x = ((unsigned)cvbf(v0.y) << 16) | (unsigned)cvbf(v0.x);
        ob.y = ((unsigned)cvbf(v0.w) << 16) | (unsigned)cvbf(v0.z);
        ob.z = ((unsigned)cvbf(v1.y) << 16) | (unsigned)cvbf(v1.x);
        ob.w = ((unsigned)cvbf(v1.w) << 16) | (unsigned)cvbf(v1.z);
        ((uint4*)outb)[(size_t)grow * 16 + cg] = ob;
    }
}

// ---------------- fused GNN layer: 16KB aliased LDS, bf16-carried h ----------------
// Gather: 16 interleaved node-chains/wave (proven best form: one 16-load group in
// flight, col prefetch one group ahead). Then GEMM1 -> Ts (bf16) -> GEMM2 -> Os
// (bf16 s) -> 16B/lane epilogue o = h_own + relu(s).
// Mid layers: bf16 carry to hb_out (ping-pong, != hb_in). Last: fp32 to outf.
__global__ __launch_bounds__(256, 4) void gnnlayer_k(
    const unsigned* __restrict__ hb_in, const int* __restrict__ rp, const int* __restrict__ col,
    const short* __restrict__ W1b, const float* __restrict__ b1,
    const short* __restrict__ W2b, const float* __restrict__ b2,
    float* __restrict__ outf, unsigned* __restrict__ hb_out, int nrows) {
    __shared__ __align__(16) char smem[16384];
    __shared__ float dflag[64];
    short8* As = (short8*)smem;
    short* TsS = (short*)smem;
    unsigned short* Os = (unsigned short*)smem;
    int t = threadIdx.x;
    int rowbase = blockIdx.x * 64;
    int lane = t & 63;
    int wv = __builtin_amdgcn_readfirstlane(t >> 6);  // 0..3

    // ---- gather-aggregate: this wave owns nodes nbase..nbase+16 ----
    {
        int nbase = rowbase + wv * 16;
        int rb[17];
#pragma unroll
        for (int i = 0; i <= 16; ++i)
            rb[i] = __builtin_amdgcn_readfirstlane(rp[min(nbase + i, N_NODES)]);
        int d[16];
        int maxd = 0;
#pragma unroll
        for (int i = 0; i < 16; ++i) {
            d[i] = rb[i + 1] - rb[i];
            maxd = max(maxd, d[i]);
        }

        float ax[16], ay[16];
        int u[16];
#pragma unroll
        for (int i = 0; i < 16; ++i) {
            ax[i] = 0.f;
            ay[i] = 0.f;
            u[i] = 0;
        }
#pragma unroll
        for (int i = 0; i < 16; ++i)
            if (0 < d[i]) u[i] = col[rb[i]];  // wave-uniform -> s_load

        for (int j = 0; j < maxd; ++j) {
            unsigned p[16];
            // issue all active gathers first (independent -> in flight together)
#pragma unroll
            for (int i = 0; i < 16; ++i)
                p[i] = (j < d[i]) ? hb_in[(size_t)u[i] * 64 + lane] : 0u;
            int jn = j + 1;
#pragma unroll
            for (int i = 0; i < 16; ++i)
                if (jn < d[i]) u[i] = col[rb[i] + jn];
#pragma unroll
            for (int i = 0; i < 16; ++i) {
                ax[i] += bflo(p[i]);
                ay[i] += bfhi(p[i]);
            }
        }

        // flush node means (inv_deg-scaled bf16) into swizzled As; dflag from degree
        unsigned* AsU = (unsigned*)As;
        int g = lane >> 2;
        int dw = lane & 3;
#pragma unroll
        for (int i = 0; i < 16; ++i) {
            float inv = 1.0f / fmaxf((float)d[i], 1.0f);
            unsigned pv = ((unsigned)cvbf(ay[i] * inv) << 16) | (unsigned)cvbf(ax[i] * inv);
            int r = wv * 16 + i;
            AsU[(r * 16 + (g ^ (r & 7))) * 4 + dw] = pv;
            if (lane == 0) dflag[r] = (d[i] > 0) ? 1.0f : 0.0f;
        }
    }

    int c0 = wv * 32;
    int lrow = lane & 15;
    int lk = lane >> 4;
    int swz = lrow & 7;

    const short8* W1v = (const short8*)W1b;
    short8 bw[2][4];
#pragma unroll
    for (int ct = 0; ct < 2; ++ct)
#pragma unroll
        for (int ks = 0; ks < 4; ++ks)
            bw[ct][ks] = W1v[(size_t)(c0 + ct * 16 + lrow) * 16 + ks * 4 + lk];

    __syncthreads();  // As + dflag complete

    f32x4 zero4 = {0.f, 0.f, 0.f, 0.f};
    f32x4 acc[4][2];
#pragma unroll
    for (int rt = 0; rt < 4; ++rt) {
        acc[rt][0] = zero4;
        acc[rt][1] = zero4;
    }
#pragma unroll
    for (int ks = 0; ks < 4; ++ks) {
        short8 a[4];
#pragma unroll
        for (int rt = 0; rt < 4; ++rt)
            a[rt] = As[(rt * 16 + lrow) * 16 + ((ks * 4 + lk) ^ swz)];
#pragma unroll
        for (int rt = 0; rt < 4; ++rt) {
            acc[rt][0] = __builtin_amdgcn_mfma_f32_16x16x32_bf16(a[rt], bw[0][ks], acc[rt][0], 0, 0, 0);
            acc[rt][1] = __builtin_amdgcn_mfma_f32_16x16x32_bf16(a[rt], bw[1][ks], acc[rt][1], 0, 0, 0);
        }
    }

    const short8* W2v = (const short8*)W2b;
    short8 bw2[2][4];
#pragma unroll
    for (int ct = 0; ct < 2; ++ct)
#pragma unroll
        for (int ks = 0; ks < 4; ++ks)
            bw2[ct][ks] = W2v[(size_t)(c0 + ct * 16 + lrow) * 16 + ks * 4 + lk];

    float b1v[2] = {b1[c0 + lrow], b1[c0 + 16 + lrow]};
    __syncthreads();  // all As reads done; region becomes T tile
#pragma unroll
    for (int rt = 0; rt < 4; ++rt) {
#pragma unroll
        for (int ct = 0; ct < 2; ++ct) {
            int c = c0 + ct * 16 + lrow;
            int gh = c >> 3;
#pragma unroll
            for (int reg = 0; reg < 4; ++reg) {
                int rl = rt * 16 + lk * 4 + reg;  // C/D: row=(lane>>4)*4+reg
                float tv = acc[rt][ct][reg] + b1v[ct] * dflag[rl];
                TsS[rl * 128 + ((gh ^ (rl & 7)) << 3) + (c & 7)] = (short)cvbf(tv);
            }
        }
    }
    __syncthreads();  // T complete

    f32x4 acc2[4][2];
#pragma unroll
    for (int rt = 0; rt < 4; ++rt) {
        acc2[rt][0] = zero4;
        acc2[rt][1] = zero4;
    }
#pragma unroll
    for (int ks = 0; ks < 4; ++ks) {
        short8 a[4];
#pragma unroll
        for (int rt = 0; rt < 4; ++rt)
            a[rt] = As[(rt * 16 + lrow) * 16 + ((ks * 4 + lk) ^ swz)];  // region holds T now
#pragma unroll
        for (int rt = 0; rt < 4; ++rt) {
            acc2[rt][0] = __builtin_amdgcn_mfma_f32_16x16x32_bf16(a[rt], bw2[0][ks], acc2[rt][0], 0, 0, 0);
            acc2[rt][1] = __builtin_amdgcn_mfma_f32_16x16x32_bf16(a[rt], bw2[1][ks], acc2[rt][1], 0, 0, 0);
        }
    }

    float b2v[2] = {b2[c0 + lrow], b2[c0 + 16 + lrow]};
    __syncthreads();  // all T reads done; region becomes s tile (bf16)
#pragma unroll
    for (int rt = 0; rt < 4; ++rt) {
#pragma unroll
        for (int ct = 0; ct < 2; ++ct) {
            int c = c0 + ct * 16 + lrow;
            int gh = c >> 3;
#pragma unroll
            for (int reg = 0; reg < 4; ++reg) {
                int rl = rt * 16 + lk * 4 + reg;
                Os[rl * 128 + ((gh ^ (rl & 7)) << 3) + (c & 7)] =
                    cvbf(acc2[rt][ct][reg] + b2v[ct]);
            }
        }
    }
    __syncthreads();

    // epilogue: o = h_own + relu(s). 16B/lane accesses throughout.
    const uint4* Hb16 = (const uint4*)hb_in;
#pragma unroll
    for (int ch = 0; ch < 4; ++ch) {
        int flat = ch * 256 + t;  // 0..1023 : 64 rows x 16 col-granules(8)
        int row = flat >> 4;
        int cg = flat & 15;
        int grow = rowbase + row;
        if (grow >= nrows) continue;
        uint4 sv = *(const uint4*)&Os[row * 128 + ((cg ^ (row & 7)) << 3)];
        uint4 hv = Hb16[(size_t)grow * 16 + cg];
        float o[8];
        const unsigned* sp = (const unsigned*)&sv;
        const unsigned* hp = (const unsigned*)&hv;
#pragma unroll
        for (int j = 0; j < 4; ++j) {
            o[2 * j + 0] = bflo(hp[j]) + fmaxf(bflo(sp[j]), 0.f);
            o[2 * j + 1] = bfhi(hp[j]) + fmaxf(bfhi(sp[j]), 0.f);
        }
        if (hb_out) {
            uint4 ob;
            ob.x = ((unsigned)cvbf(o[1]) << 16) | (unsigned)cvbf(o[0]);
            ob.y = ((unsigned)cvbf(o[3]) << 16) | (unsigned)cvbf(o[2]);
            ob.z = ((unsigned)cvbf(o[5]) << 16) | (unsigned)cvbf(o[4]);
            ob.w = ((unsigned)cvbf(o[7]) << 16) | (unsigned)cvbf(o[6]);
            ((uint4*)hb_out)[(size_t)grow * 16 + cg] = ob;
        }
        if (outf) {
            float4 f0 = make_float4(o[0], o[1], o[2], o[3]);
            float4 f1 = make_float4(o[4], o[5], o[6], o[7]);
            ((float4*)outf)[(size_t)grow * 32 + cg * 2 + 0] = f0;
            ((float4*)outf)[(size_t)grow * 32 + cg * 2 + 1] = f1;
        }
    }
}

extern "C" void kernel_launch(void* const* d_in, const int* in_sizes, int n_in,
                              void* d_out, int out_size, void* d_ws, size_t ws_size,
                              hipStream_t stream) {
    const float* x = (const float*)d_in[0];
    const float* Wi = (const float*)d_in[1];
    const float* bi = (const float*)d_in[2];
    const float* Wm = (const float*)d_in[3];
    const float* bm = (const float*)d_in[4];
    const float* Wu = (const float*)d_in[5];
    const float* bu = (const float*)d_in[6];
    const int* edge = (const int*)d_in[7];
    float* h = (float*)d_out;

    char* ws = (char*)d_ws;
    size_t off = 0;
    auto alloc = [&](size_t bytes) {
        void* p = ws + off;
        off += (bytes + 255) & ~(size_t)255;
        return p;
    };
    // ping-pong bf16 h buffers (the carried representation between layers)
    unsigned* hbuf[2];
    hbuf[0] = (unsigned*)alloc((size_t)N_NODES * D * 2);
    hbuf[1] = (unsigned*)alloc((size_t)N_NODES * D * 2);
    unsigned short* Wi_bf = (unsigned short*)alloc((size_t)D * D * 2);
    unsigned short* Wm_bf = (unsigned short*)alloc((size_t)NLAYERS * D * D * 2);
    unsigned short* Wu_bf = (unsigned short*)alloc((size_t)NLAYERS * D * D * 2);
    int* cnt = (int*)alloc((size_t)N_NODES * sizeof(int));
    int* rp = (int*)alloc((size_t)(N_NODES + 1) * sizeof(int));
    int* fill = (int*)alloc((size_t)N_NODES * sizeof(int));
    int* bsum = (int*)alloc(1024 * sizeof(int));
    int* col = (int*)alloc((size_t)N_EDGES * sizeof(int));

    const int scan_blocks = (N_NODES + 1023) / 1024;  // 98
    const int edge_blocks = (N_EDGES + 255) / 256;    // 2500
    const int gemm_blocks = (N_NODES + 63) / 64;      // 1563
    const int wconv_n = (D * D / 4) * 9;              // 36864 float4s
    const int wconv_blocks = (wconv_n + 255) / 256;   // 144

    // CSR build
    hipMemsetAsync(cnt, 0, (size_t)N_NODES * sizeof(int), stream);
    count_kernel<<<edge_blocks, 256, 0, stream>>>(edge, cnt);
    scan_local<<<scan_blocks, 256, 0, stream>>>(cnt, rp, bsum);
    scan_add<<<scan_blocks, 256, 0, stream>>>(rp, fill, bsum);
    fill_kernel<<<edge_blocks, 256, 0, stream>>>(edge, fill, col);

    // all weights -> bf16 in one dispatch
    wconv_all<<<wconv_blocks, 256, 0, stream>>>(Wi, Wm, Wu, Wi_bf, Wm_bf, Wu_bf);

    // input projection: hbuf[0] = bf16(x @ Wi^T + bi)
    proj_k<<<gemm_blocks, 256, 0, stream>>>(x, (const short*)Wi_bf, bi, hbuf[0], N_NODES);

    for (int l = 0; l < NLAYERS; ++l) {
        // layer l: read hbuf[l&1]; mid -> bf16 carry into hbuf[(l+1)&1]; last -> fp32 d_out
        unsigned* hb_out = (l == NLAYERS - 1) ? nullptr : hbuf[(l + 1) & 1];
        float* outf = (l == NLAYERS - 1) ? h : nullptr;
        gnnlayer_k<<<gemm_blocks, 256, 0, stream>>>(
            hbuf[l & 1], rp, col,
            (const short*)(Wm_bf + (size_t)l * D * D), bm + (size_t)l * D,
            (const short*)(Wu_bf + (size_t)l * D * D), bu + (size_t)l * D, outf, hb_out,
            N_NODES);
    }
}